// Round 9
// baseline (3686.540 us; speedup 1.0000x reference)
//
#include <hip/hip_runtime.h>
#include <hip/hip_bf16.h>

#define N_NODES 100000
#define N_EDGES 1000000
#define NLAYERS 10

typedef __hip_bfloat16 bf16;
typedef __attribute__((ext_vector_type(8))) short short8;
typedef __attribute__((ext_vector_type(4))) float f32x4;

// flag-aware float load: isbf=1 -> treat p as bf16 array, else fp32
__device__ __forceinline__ float ldf(const void* p, long i, int isbf){
  if (isbf){
    unsigned short u = ((const unsigned short*)p)[i];
    union{unsigned u; float f;} c; c.u = ((unsigned)u) << 16; return c.f;
  }
  return ((const float*)p)[i];
}

__device__ __forceinline__ int esrc(const int* ei, int e, int i64){
  return i64 ? ei[2*e] : ei[e];
}
__device__ __forceinline__ int edst(const int* ei, int e, int i64){
  return i64 ? ei[2*N_EDGES + 2*e] : ei[N_EDGES + e];
}

// split fp32 -> bf16 hi (truncate) + bf16 lo (residual)
__device__ __forceinline__ void split8(const float* p, short8& hi, short8& lo){
  float4 a = *(const float4*)p; float4 b = *(const float4*)(p+4);
  float v[8] = {a.x,a.y,a.z,a.w,b.x,b.y,b.z,b.w};
  #pragma unroll
  for (int i = 0; i < 8; i++){
    union{float f; unsigned u;} t; t.f = v[i];
    unsigned hu = t.u & 0xffff0000u;
    hi[i] = (short)(hu >> 16);
    union{unsigned u; float f;} hf; hf.u = hu;
    union{float f; unsigned u;} t2; t2.f = v[i] - hf.f;
    lo[i] = (short)(t2.u >> 16);
  }
}

__device__ __forceinline__ void splitval(float val, short& hi, short& lo){
  union{float f; unsigned u;} t; t.f = val;
  unsigned hu = t.u & 0xffff0000u;
  hi = (short)(hu >> 16);
  union{unsigned u; float f;} hf; hf.u = hu;
  union{float f; unsigned u;} t2; t2.f = val - hf.f;
  lo = (short)(t2.u >> 16);
}

// ---------------- dtype detection (parallel) ----------------
__global__ __launch_bounds__(256) void k_detect(const unsigned* __restrict__ xw,
                                                const int* __restrict__ ei,
                                                int* __restrict__ flag,
                                                int* __restrict__ eflag){
  __shared__ int s[256];
  __shared__ int t[256];
  int tid = threadIdx.x;
  int cnt = 0;
  #pragma unroll
  for (int i = 0; i < 16; i++){
    unsigned u = xw[tid*16 + i];
    unsigned lo = u & 0xffffu;
    unsigned e = (lo >> 7) & 0xff;
    if ((e >= 96 && e <= 150) || lo == 0) cnt++;
  }
  int nz = 0;
  #pragma unroll
  for (int i = 0; i < 8; i++) nz |= ei[2*(tid*8 + i) + 1];
  s[tid] = cnt; t[tid] = nz; __syncthreads();
  for (int o = 128; o > 0; o >>= 1){
    if (tid < o){ s[tid] += s[tid+o]; t[tid] |= t[tid+o]; }
    __syncthreads();
  }
  if (tid == 0){
    *flag = (s[0] >= 3000) ? 1 : 0;
    *eflag = (t[0] == 0) ? 1 : 0;
  }
}

// ---------------- CSR build ----------------
__global__ __launch_bounds__(256) void k_count(const int* __restrict__ ei,
    int* __restrict__ cnt, const int* __restrict__ eflag){
  int i64 = *eflag;
  int e = blockIdx.x*256 + threadIdx.x;
  if (e < N_EDGES) atomicAdd(&cnt[edst(ei, e, i64)], 1);
}

__global__ __launch_bounds__(1024) void k_scan1(const int* __restrict__ cnt,
    int* __restrict__ rowptr, int* __restrict__ bsum){
  __shared__ int lds[1024];
  int tid = threadIdx.x;
  int i = blockIdx.x*1024 + tid;
  int v = (i < N_NODES) ? cnt[i] : 0;
  lds[tid] = v; __syncthreads();
  for (int off = 1; off < 1024; off <<= 1){
    int t = (tid >= off) ? lds[tid - off] : 0;
    __syncthreads();
    lds[tid] += t;
    __syncthreads();
  }
  if (i < N_NODES) rowptr[i] = lds[tid] - v;
  if (tid == 1023) bsum[blockIdx.x] = lds[1023];
}

__global__ __launch_bounds__(128) void k_scan2(int* __restrict__ bsum, int* __restrict__ rowptr){
  __shared__ int lds[128];
  int tid = threadIdx.x;
  int v = (tid < 98) ? bsum[tid] : 0;
  lds[tid] = v; __syncthreads();
  for (int off = 1; off < 128; off <<= 1){
    int t = (tid >= off) ? lds[tid - off] : 0;
    __syncthreads();
    lds[tid] += t;
    __syncthreads();
  }
  if (tid < 98) bsum[tid] = lds[tid] - v;
  if (tid == 127) rowptr[N_NODES] = lds[127];
}

__global__ __launch_bounds__(1024) void k_scan3(int* __restrict__ rowptr,
    int* __restrict__ cursor, const int* __restrict__ bsum){
  int i = blockIdx.x*1024 + threadIdx.x;
  if (i < N_NODES){
    int r = rowptr[i] + bsum[blockIdx.x];
    rowptr[i] = r;
    cursor[i] = r;
  }
}

__global__ __launch_bounds__(256) void k_fill(const int* __restrict__ ei,
    int* __restrict__ cursor, unsigned short* __restrict__ c16,
    unsigned char* __restrict__ c8, const int* __restrict__ eflag){
  int i64 = *eflag;
  int e = blockIdx.x*256 + threadIdx.x;
  if (e < N_EDGES){
    int d = edst(ei, e, i64);
    int p = atomicAdd(&cursor[d], 1);
    int s = esrc(ei, e, i64);
    c16[p] = (unsigned short)(s & 0xffff);
    c8[p]  = (unsigned char)(s >> 16);
  }
}

// ---------------- param prep: split+swizzle weights, small params fp32 ----------------
// bases (elements): qkv (l,g): (l*2+g)*13824 (NTcols=144) | oproj 276480+l*7680 (80)
// | ffn1 353280+l*15360 (160) | ffn2 506880+l*12800 (80)
__global__ __launch_bounds__(256) void k_prep(
    const void* Wq, const void* Wk, const void* Wv, const void* Wo,
    const void* W1, const void* W2, const void* bo, const void* b1,
    const void* b2, const void* We, const void* be,
    const void* Wr0, const void* br0, const void* Wr1, const void* br1,
    const void* Wr2, const void* br2,
    short* __restrict__ whi, short* __restrict__ wlo,
    float* __restrict__ pfS, const int* __restrict__ flagp){
  const int isbf = *flagp;
  int idx = blockIdx.x*256 + threadIdx.x;
  if (idx < 634880){
    float val = 0.f;
    if (idx < 276480){
      int l = idx / 27648; int r = idx % 27648;
      int g = r / 13824; int r2 = r % 13824;
      int kb = r2 / 4608; int r3 = r2 % 4608;
      int n144 = r3 / 32; int kk = r3 % 32;
      int sec = n144 / 48; int n = n144 % 48;
      int k = kb*32 + kk;
      if (k < 80 && n < 40){
        const void* src = (sec == 0) ? Wq : (sec == 1) ? Wk : Wv;
        val = ldf(src, (long)l*6400 + k*80 + g*40 + n, isbf);
      }
    } else if (idx < 353280){
      int r = idx - 276480;
      int l = r / 7680; int r2 = r % 7680;
      int kb = r2 / 2560; int n = (r2 % 2560) / 32; int kk = r2 % 32;
      int k = kb*32 + kk;
      if (k < 80) val = ldf(Wo, (long)l*6400 + k*80 + n, isbf);
    } else if (idx < 506880){
      int r = idx - 353280;
      int l = r / 15360; int r2 = r % 15360;
      int kb = r2 / 5120; int n = (r2 % 5120) / 32; int kk = r2 % 32;
      int k = kb*32 + kk;
      if (k < 80) val = ldf(W1, (long)l*12800 + k*160 + n, isbf);
    } else {
      int r = idx - 506880;
      int l = r / 12800; int r2 = r % 12800;
      int kb = r2 / 2560; int n = (r2 % 2560) / 32; int kk = r2 % 32;
      int k = kb*32 + kk;
      val = ldf(W2, (long)l*12800 + k*80 + n, isbf);
    }
    union{float f; unsigned u;} t; t.f = val;
    unsigned hu = t.u & 0xffff0000u;
    whi[idx] = (short)(hu >> 16);
    union{unsigned u; float f;} hf; hf.u = hu;
    union{float f; unsigned u;} t2; t2.f = val - hf.f;
    wlo[idx] = (short)(t2.u >> 16);
    return;
  }
  int p = idx - 634880;
  if (p < 8144){
    float v;
    if      (p < 800)  v = ldf(bo,  p,        isbf);
    else if (p < 2400) v = ldf(b1,  p-800,    isbf);
    else if (p < 3200) v = ldf(b2,  p-2400,   isbf);
    else if (p < 3920) v = ldf(We,  p-3200,   isbf);
    else if (p < 4000) v = ldf(be,  p-3920,   isbf);
    else if (p < 7200) v = ldf(Wr0, p-4000,   isbf);
    else if (p < 7240) v = ldf(br0, p-7200,   isbf);
    else if (p < 8040) v = ldf(Wr1, p-7240,   isbf);
    else if (p < 8060) v = ldf(br1, p-8040,   isbf);
    else if (p < 8140) v = ldf(Wr2, p-8060,   isbf);
    else               v = ldf(br2, p-8140,   isbf);
    pfS[p] = v;
  }
}

// ---------------- embedding ----------------
__global__ __launch_bounds__(256) void k_embed(const void* __restrict__ x,
    const float* __restrict__ WeF, const float* __restrict__ beF,
    float* __restrict__ h, const int* __restrict__ flagp){
  __shared__ float Wl[720];
  __shared__ float bl[80];
  const int isbf = *flagp;
  int tid = threadIdx.x;
  for (int i = tid; i < 720; i += 256) Wl[i] = WeF[i];
  if (tid < 80) bl[tid] = beF[tid];
  __syncthreads();
  long idx = (long)blockIdx.x*256 + tid;
  int n = (int)(idx / 80); int c = (int)(idx - (long)n*80);
  float s = bl[c];
  #pragma unroll
  for (int k = 0; k < 9; k++) s = fmaf(ldf(x, (long)n*9 + k, isbf), Wl[k*80 + c], s);
  h[idx] = s;
}

// ---------------- QKV GEMM: row-blocked (R=2), split-bf16 MFMA ----------------
// wave owns 32 rows; 9 tiles of 144 padded cols (3 sections of 48, 40 real).
__global__ __launch_bounds__(256) void k_qkv(
    const float* __restrict__ h,
    const short* __restrict__ Whi, const short* __restrict__ Wlo,
    float* __restrict__ outQ, long slot){
  const int tid  = threadIdx.x;
  const int w    = tid >> 6;
  const int lane = tid & 63;
  const int m16  = lane & 15;
  const int q    = lane >> 4;
  const int rowbase = blockIdx.x*128 + w*32;

  f32x4 acc[2][9];
  #pragma unroll
  for (int rg = 0; rg < 2; rg++)
    #pragma unroll
    for (int t = 0; t < 9; t++) acc[rg][t] = (f32x4){0.f,0.f,0.f,0.f};

  #pragma unroll
  for (int kb = 0; kb < 3; kb++){
    int k0 = kb*32 + q*8;
    short8 ahi[2], alo[2];
    #pragma unroll
    for (int rg = 0; rg < 2; rg++){
      ahi[rg] = (short8)0; alo[rg] = (short8)0;
      if (k0 < 80){
        int grow = rowbase + rg*16 + m16;
        if (grow >= N_NODES) grow = N_NODES-1;
        split8(h + (long)grow*80 + k0, ahi[rg], alo[rg]);
      }
    }
    #pragma unroll
    for (int t = 0; t < 9; t++){
      long wi = ((long)(kb*144 + t*16 + m16))*32 + q*8;
      short8 bhi = *(const short8*)(Whi + wi);
      short8 blo = *(const short8*)(Wlo + wi);
      #pragma unroll
      for (int rg = 0; rg < 2; rg++){
        acc[rg][t] = __builtin_amdgcn_mfma_f32_16x16x32_bf16(alo[rg], bhi, acc[rg][t], 0, 0, 0);
        acc[rg][t] = __builtin_amdgcn_mfma_f32_16x16x32_bf16(ahi[rg], blo, acc[rg][t], 0, 0, 0);
        acc[rg][t] = __builtin_amdgcn_mfma_f32_16x16x32_bf16(ahi[rg], bhi, acc[rg][t], 0, 0, 0);
      }
    }
  }
  #pragma unroll
  for (int t = 0; t < 9; t++){
    int sec = t/3; int c = (t%3)*16 + m16;
    if (c < 40){
      float* ob = outQ + (long)sec*slot;
      #pragma unroll
      for (int rg = 0; rg < 2; rg++){
        #pragma unroll
        for (int r2 = 0; r2 < 4; r2++){
          int grow = rowbase + rg*16 + q*4 + r2;
          if (grow < N_NODES) ob[(long)grow*40 + c] = acc[rg][t][r2];
        }
      }
    }
  }
}

// ---------------- fused post-attention: oproj + FFN1 + FFN2 ----------------
// block = 64 rows, 4 waves split output col-tiles; intermediates in LDS.
__global__ __launch_bounds__(256,2) void k_post(
    const float* __restrict__ attn0, const float* __restrict__ attn1,
    float* __restrict__ h,
    const short* __restrict__ WhiO, const short* __restrict__ WloO,
    const short* __restrict__ Whi1, const short* __restrict__ Wlo1,
    const short* __restrict__ Whi2, const short* __restrict__ Wlo2,
    const float* __restrict__ bo, const float* __restrict__ b1,
    const float* __restrict__ b2){
  __shared__ float hs[64*84];        // h_new, row stride 84
  __shared__ short t_hi[64*168];     // relu(ffn1) split-hi, row stride 168
  __shared__ short t_lo[64*168];
  const int tid  = threadIdx.x;
  const int w    = tid >> 6;
  const int lane = tid & 63;
  const int m16  = lane & 15;
  const int q    = lane >> 4;
  const int row0 = blockIdx.x*64;

  // ---- stage 1: oproj (K=80 split 40|40, 5 tiles: w0->{0,4}, w1..3->{1,2,3})
  {
    const int nt = (w==0) ? 2 : 1;
    f32x4 acc[4][2];
    #pragma unroll
    for (int rg = 0; rg < 4; rg++)
      #pragma unroll
      for (int it = 0; it < 2; it++) acc[rg][it] = (f32x4){0.f,0.f,0.f,0.f};
    #pragma unroll
    for (int kb = 0; kb < 3; kb++){
      int k0 = kb*32 + q*8;
      short8 ahi[4], alo[4];
      #pragma unroll
      for (int rg = 0; rg < 4; rg++){
        ahi[rg] = (short8)0; alo[rg] = (short8)0;
        if (k0 < 80){
          int grow = row0 + rg*16 + m16;
          if (grow >= N_NODES) grow = N_NODES-1;
          const float* p = (k0 < 40) ? attn0 + (long)grow*40 + k0
                                     : attn1 + (long)grow*40 + (k0-40);
          split8(p, ahi[rg], alo[rg]);
        }
      }
      for (int it = 0; it < nt; it++){
        int t = (it==0) ? w : 4;
        long wi = ((long)(kb*80 + t*16 + m16))*32 + q*8;
        short8 bhi = *(const short8*)(WhiO + wi);
        short8 blo = *(const short8*)(WloO + wi);
        #pragma unroll
        for (int rg = 0; rg < 4; rg++){
          acc[rg][it] = __builtin_amdgcn_mfma_f32_16x16x32_bf16(alo[rg], bhi, acc[rg][it], 0, 0, 0);
          acc[rg][it] = __builtin_amdgcn_mfma_f32_16x16x32_bf16(ahi[rg], blo, acc[rg][it], 0, 0, 0);
          acc[rg][it] = __builtin_amdgcn_mfma_f32_16x16x32_bf16(ahi[rg], bhi, acc[rg][it], 0, 0, 0);
        }
      }
    }
    for (int it = 0; it < nt; it++){
      int t = (it==0) ? w : 4;
      int col = t*16 + m16;
      float bb = bo[col];
      #pragma unroll
      for (int rg = 0; rg < 4; rg++){
        #pragma unroll
        for (int r2 = 0; r2 < 4; r2++){
          int rloc = rg*16 + q*4 + r2;
          int grow = row0 + rloc;
          float resid = (grow < N_NODES) ? h[(long)grow*80 + col] : 0.f;
          hs[rloc*84 + col] = acc[rg][it][r2] + bb + resid;
        }
      }
    }
  }
  __syncthreads();

  // ---- stage 2: ffn1 (K=80 from hs LDS, 10 tiles: w,w+4,w+8)
  {
    const int nt = (w < 2) ? 3 : 2;
    f32x4 acc[4][3];
    #pragma unroll
    for (int rg = 0; rg < 4; rg++)
      #pragma unroll
      for (int it = 0; it < 3; it++) acc[rg][it] = (f32x4){0.f,0.f,0.f,0.f};
    #pragma unroll
    for (int kb = 0; kb < 3; kb++){
      int k0 = kb*32 + q*8;
      short8 ahi[4], alo[4];
      #pragma unroll
      for (int rg = 0; rg < 4; rg++){
        ahi[rg] = (short8)0; alo[rg] = (short8)0;
        if (k0 < 80){
          int rloc = rg*16 + m16;
          split8(&hs[rloc*84 + k0], ahi[rg], alo[rg]);
        }
      }
      for (int it = 0; it < nt; it++){
        int t = w + it*4;
        long wi = ((long)(kb*160 + t*16 + m16))*32 + q*8;
        short8 bhi = *(const short8*)(Whi1 + wi);
        short8 blo = *(const short8*)(Wlo1 + wi);
        #pragma unroll
        for (int rg = 0; rg < 4; rg++){
          acc[rg][it] = __builtin_amdgcn_mfma_f32_16x16x32_bf16(alo[rg], bhi, acc[rg][it], 0, 0, 0);
          acc[rg][it] = __builtin_amdgcn_mfma_f32_16x16x32_bf16(ahi[rg], blo, acc[rg][it], 0, 0, 0);
          acc[rg][it] = __builtin_amdgcn_mfma_f32_16x16x32_bf16(ahi[rg], bhi, acc[rg][it], 0, 0, 0);
        }
      }
    }
    for (int it = 0; it < nt; it++){
      int t = w + it*4;
      int col = t*16 + m16;
      float bb = b1[col];
      #pragma unroll
      for (int rg = 0; rg < 4; rg++){
        #pragma unroll
        for (int r2 = 0; r2 < 4; r2++){
          int rloc = rg*16 + q*4 + r2;
          float val = fmaxf(acc[rg][it][r2] + bb, 0.f);
          short hi16, lo16; splitval(val, hi16, lo16);
          t_hi[rloc*168 + col] = hi16;
          t_lo[rloc*168 + col] = lo16;
        }
      }
    }
  }
  __syncthreads();

  // ---- stage 3: ffn2 (K=160 from t_hi/t_lo LDS, 5 tiles like stage 1)
  {
    const int nt = (w==0) ? 2 : 1;
    f32x4 acc[4][2];
    #pragma unroll
    for (int rg = 0; rg < 4; rg++)
      #pragma unroll
      for (int it = 0; it < 2; it++) acc[rg][it] = (f32x4){0.f,0.f,0.f,0.f};
    #pragma unroll
    for (int kb = 0; kb < 5; kb++){
      int k0 = kb*32 + q*8;
      short8 ahi[4], alo[4];
      #pragma unroll
      for (int rg = 0; rg < 4; rg++){
        int rloc = rg*16 + m16;
        ahi[rg] = *(const short8*)(&t_hi[rloc*168 + k0]);
        alo[rg] = *(const short8*)(&t_lo[rloc*168 + k0]);
      }
      for (int it = 0; it < nt; it++){
        int t = (it==0) ? w : 4;
        long wi = ((long)(kb*80 + t*16 + m16))*32 + q*8;
        short8 bhi = *(const short8*)(Whi2 + wi);
        short8 blo = *(const short8*)(Wlo2 + wi);
        #pragma unroll
        for (int rg = 0; rg < 4; rg++){
          acc[rg][it] = __builtin_amdgcn_mfma_f32_16x16x32_bf16(alo[rg], bhi, acc[rg][it], 0, 0, 0);
          acc[rg][it] = __builtin_amdgcn_mfma_f32_16x16x32_bf16(ahi[rg], blo, acc[rg][it], 0, 0, 0);
          acc[rg][it] = __builtin_amdgcn_mfma_f32_16x16x32_bf16(ahi[rg], bhi, acc[rg][it], 0, 0, 0);
        }
      }
    }
    for (int it = 0; it < nt; it++){
      int t = (it==0) ? w : 4;
      int col = t*16 + m16;
      float bb = b2[col];
      #pragma unroll
      for (int rg = 0; rg < 4; rg++){
        #pragma unroll
        for (int r2 = 0; r2 < 4; r2++){
          int rloc = rg*16 + q*4 + r2;
          int grow = row0 + rloc;
          if (grow < N_NODES)
            h[(long)grow*80 + col] = acc[rg][it][r2] + bb + hs[rloc*84 + col];
        }
      }
    }
  }
}

// ---------------- edge-softmax attention: wave per node ----------------
__global__ __launch_bounds__(256) void k_attn(
    float* __restrict__ Qg, const float* __restrict__ Kg, const float* __restrict__ Vg,
    const int* __restrict__ rowptr, const unsigned short* __restrict__ c16,
    const unsigned char* __restrict__ c8){
  int n = (blockIdx.x*256 + threadIdx.x) >> 6;
  int lane = threadIdx.x & 63;
  int el = lane >> 2;
  int hh = lane & 3;
  const float* qp = Qg + (long)n*40 + hh*10;
  float qv[10];
  #pragma unroll
  for (int i = 0; i < 5; i++){ float2 t = *(const float2*)(qp + 2*i); qv[2*i]=t.x; qv[2*i+1]=t.y; }
  float acc[10];
  #pragma unroll
  for (int i = 0; i < 10; i++) acc[i] = 0.f;
  float z = 0.f;
  int e0 = rowptr[n], e1 = rowptr[n+1];
  for (int j0 = e0; j0 < e1; j0 += 16){
    int j = j0 + el;
    bool valid = (j < e1);
    int jj = valid ? j : e0;
    int src = (int)c16[jj] | ((int)c8[jj] << 16);
    const float* kp = Kg + (long)src*40 + hh*10;
    const float* vp = Vg + (long)src*40 + hh*10;
    float dot = 0.f;
    #pragma unroll
    for (int i = 0; i < 5; i++){
      float2 kv = *(const float2*)(kp + 2*i);
      dot = fmaf(kv.x, qv[2*i], dot);
      dot = fmaf(kv.y, qv[2*i+1], dot);
    }
    float sc = fminf(fmaxf(dot * 0.31622776601683794f, -5.f), 5.f);
    float s = valid ? __expf(sc) : 0.f;
    z += s;
    #pragma unroll
    for (int i = 0; i < 5; i++){
      float2 vv = *(const float2*)(vp + 2*i);
      acc[2*i]   = fmaf(s, vv.x, acc[2*i]);
      acc[2*i+1] = fmaf(s, vv.y, acc[2*i+1]);
    }
  }
  #pragma unroll
  for (int m = 4; m <= 32; m <<= 1){
    z += __shfl_xor(z, m, 64);
    #pragma unroll
    for (int i = 0; i < 10; i++) acc[i] += __shfl_xor(acc[i], m, 64);
  }
  if (el == 0){
    float inv = 1.f / (z + 1e-6f);
    float* op = Qg + (long)n*40 + hh*10;
    #pragma unroll
    for (int i = 0; i < 5; i++){
      float2 o; o.x = acc[2*i]*inv; o.y = acc[2*i+1]*inv;
      *(float2*)(op + 2*i) = o;
    }
  }
}

// ---------------- MLP readout 80->40->20->4, fp32 output ----------------
__global__ __launch_bounds__(256) void k_readout(const float* __restrict__ h,
    const float* __restrict__ roF,
    float* __restrict__ out){
  __shared__ float w0[3200], w1[800], w2[80], bb0[40], bb1[20], bb2[4];
  int tid = threadIdx.x;
  for (int i = tid; i < 3200; i += 256) w0[i] = roF[i];
  for (int i = tid; i < 800;  i += 256) w1[i] = roF[3240 + i];
  if (tid < 80) w2[tid]  = roF[4060 + tid];
  if (tid < 40) bb0[tid] = roF[3200 + tid];
  if (tid < 20) bb1[tid] = roF[4040 + tid];
  if (tid < 4)  bb2[tid] = roF[4140 + tid];
  __syncthreads();
  int n = blockIdx.x*256 + tid;
  if (n >= N_NODES) return;
  float t0[40];
  #pragma unroll
  for (int c = 0; c < 40; c++) t0[c] = bb0[c];
  for (int k4 = 0; k4 < 20; k4++){
    float4 hv = *(const float4*)(h + (size_t)n*80 + k4*4);
    float hx[4] = {hv.x, hv.y, hv.z, hv.w};
    #pragma unroll
    for (int j = 0; j < 4; j++){
      int k = k4*4 + j;
      #pragma unroll
      for (int c = 0; c < 40; c++) t0[c] = fmaf(hx[j], w0[k*40 + c], t0[c]);
    }
  }
  float t1[20];
  #pragma unroll
  for (int c = 0; c < 20; c++) t1[c] = bb1[c];
  for (int k = 0; k < 40; k++){
    float a = fmaxf(t0[k], 0.f);
    #pragma unroll
    for (int c = 0; c < 20; c++) t1[c] = fmaf(a, w1[k*20 + c], t1[c]);
  }
  float o[4];
  #pragma unroll
  for (int c = 0; c < 4; c++) o[c] = bb2[c];
  for (int k = 0; k < 20; k++){
    float a = fmaxf(t1[k], 0.f);
    #pragma unroll
    for (int c = 0; c < 4; c++) o[c] = fmaf(a, w2[k*4 + c], o[c]);
  }
  #pragma unroll
  for (int c = 0; c < 4; c++) out[n*4 + c] = o[c];
}

// ---------------- launch ----------------
extern "C" void kernel_launch(void* const* d_in, const int* in_sizes, int n_in,
                              void* d_out, int out_size, void* d_ws, size_t ws_size,
                              hipStream_t stream){
  const void* x   = d_in[0];
  const int*  ei  = (const int*)d_in[1];
  const void* We  = d_in[2];
  const void* be  = d_in[3];
  const void* Wq  = d_in[4];
  const void* Wk  = d_in[5];
  const void* Wv  = d_in[6];
  const void* Wo  = d_in[7];
  const void* bo  = d_in[8];
  const void* W1  = d_in[9];
  const void* b1  = d_in[10];
  const void* W2  = d_in[11];
  const void* b2  = d_in[12];
  const void* Wr0 = d_in[13];
  const void* br0 = d_in[14];
  const void* Wr1 = d_in[15];
  const void* br1 = d_in[16];
  const void* Wr2 = d_in[17];
  const void* br2 = d_in[18];

  char* ws = (char*)d_ws;
  int*   flag   = (int*)(ws + 0);
  int*   eflag  = (int*)(ws + 4);
  int*   bsum   = (int*)(ws + 64);                 // 98 ints
  float* h      = (float*)(ws + 1024);             // 32,000,000
  float* B      = (float*)(ws + 32001024);         // 64,000,000 (4 slots x 4e6 floats)
  short* Whi    = (short*)(ws + 96001024);         // 1,269,760
  short* Wlo    = (short*)(ws + 97270784);         // 1,269,760
  float* pfS    = (float*)(ws + 98540544);         // 32,576
  int*   rowptr = (int*)(ws + 98573120);           // 400,004
  unsigned short* c16 = (unsigned short*)(ws + 98973124);  // 2,000,000
  unsigned char*  c8  = (unsigned char*)(ws + 100973124);  // 1,000,000 -> end 101,973,124
  int*   cursor = (int*)B;                         // aliases B (dead before layers)
  float* out    = (float*)d_out;

  const long SLOT = 4000000;
  const float* boF = pfS + 0;
  const float* b1F = pfS + 800;
  const float* b2F = pfS + 2400;
  const float* WeF = pfS + 3200;
  const float* beF = pfS + 3920;
  const float* roF = pfS + 4000;

  k_detect<<<1, 256, 0, stream>>>((const unsigned*)x, ei, flag, eflag);
  hipMemsetAsync(cursor, 0, N_NODES*sizeof(int), stream);
  k_count<<<(N_EDGES+255)/256, 256, 0, stream>>>(ei, cursor, eflag);
  k_scan1<<<98, 1024, 0, stream>>>(cursor, rowptr, bsum);
  k_scan2<<<1, 128, 0, stream>>>(bsum, rowptr);
  k_scan3<<<98, 1024, 0, stream>>>(rowptr, cursor, bsum);
  k_fill<<<(N_EDGES+255)/256, 256, 0, stream>>>(ei, cursor, c16, c8, eflag);
  k_prep<<<2512, 256, 0, stream>>>(Wq, Wk, Wv, Wo, W1, W2, bo, b1, b2, We, be,
                                   Wr0, br0, Wr1, br1, Wr2, br2, Whi, Wlo, pfS, flag);
  k_embed<<<(N_NODES*80)/256, 256, 0, stream>>>(x, WeF, beF, h, flag);

  const int qblk = (N_NODES + 127) / 128;   // 782
  const int pblk = (N_NODES + 63) / 64;     // 1563
  const int ablk = N_NODES / 4;             // 25000
  for (int l = 0; l < NLAYERS; l++){
    for (int g = 0; g < 2; g++){
      k_qkv<<<qblk, 256, 0, stream>>>(
          h, Whi + (l*2+g)*13824, Wlo + (l*2+g)*13824, B + g*SLOT, SLOT);
      k_attn<<<ablk, 256, 0, stream>>>(
          B + g*SLOT, B + (g+1)*SLOT, B + (g+2)*SLOT, rowptr, c16, c8);
    }
    k_post<<<pblk, 256, 0, stream>>>(
        B, B + SLOT, h,
        Whi + 276480 + l*7680,  Wlo + 276480 + l*7680,
        Whi + 353280 + l*15360, Wlo + 353280 + l*15360,
        Whi + 506880 + l*12800, Wlo + 506880 + l*12800,
        boF + l*80, b1F + l*160, b2F + l*80);
  }
  k_readout<<<(N_NODES+255)/256, 256, 0, stream>>>(h, roF, out);
}

// Round 10
// 3090.214 us; speedup vs baseline: 1.1930x; 1.1930x over previous
//
#include <hip/hip_runtime.h>
#include <hip/hip_bf16.h>

#define N_NODES 100000
#define N_EDGES 1000000
#define NLAYERS 10

typedef __hip_bfloat16 bf16;
typedef __attribute__((ext_vector_type(8))) short short8;
typedef __attribute__((ext_vector_type(4))) float f32x4;

// flag-aware float load: isbf=1 -> treat p as bf16 array, else fp32
__device__ __forceinline__ float ldf(const void* p, long i, int isbf){
  if (isbf){
    unsigned short u = ((const unsigned short*)p)[i];
    union{unsigned u; float f;} c; c.u = ((unsigned)u) << 16; return c.f;
  }
  return ((const float*)p)[i];
}

__device__ __forceinline__ int esrc(const int* ei, int e, int i64){
  return i64 ? ei[2*e] : ei[e];
}
__device__ __forceinline__ int edst(const int* ei, int e, int i64){
  return i64 ? ei[2*N_EDGES + 2*e] : ei[N_EDGES + e];
}

// split fp32 -> bf16 hi (truncate) + bf16 lo (residual)
__device__ __forceinline__ void split8(const float* p, short8& hi, short8& lo){
  float4 a = *(const float4*)p; float4 b = *(const float4*)(p+4);
  float v[8] = {a.x,a.y,a.z,a.w,b.x,b.y,b.z,b.w};
  #pragma unroll
  for (int i = 0; i < 8; i++){
    union{float f; unsigned u;} t; t.f = v[i];
    unsigned hu = t.u & 0xffff0000u;
    hi[i] = (short)(hu >> 16);
    union{unsigned u; float f;} hf; hf.u = hu;
    union{float f; unsigned u;} t2; t2.f = v[i] - hf.f;
    lo[i] = (short)(t2.u >> 16);
  }
}

__device__ __forceinline__ void splitval(float val, short& hi, short& lo){
  union{float f; unsigned u;} t; t.f = val;
  unsigned hu = t.u & 0xffff0000u;
  hi = (short)(hu >> 16);
  union{unsigned u; float f;} hf; hf.u = hu;
  union{float f; unsigned u;} t2; t2.f = val - hf.f;
  lo = (short)(t2.u >> 16);
}

// ---------------- dtype detection (parallel) ----------------
__global__ __launch_bounds__(256) void k_detect(const unsigned* __restrict__ xw,
                                                const int* __restrict__ ei,
                                                int* __restrict__ flag,
                                                int* __restrict__ eflag){
  __shared__ int s[256];
  __shared__ int t[256];
  int tid = threadIdx.x;
  int cnt = 0;
  #pragma unroll
  for (int i = 0; i < 16; i++){
    unsigned u = xw[tid*16 + i];
    unsigned lo = u & 0xffffu;
    unsigned e = (lo >> 7) & 0xff;
    if ((e >= 96 && e <= 150) || lo == 0) cnt++;
  }
  int nz = 0;
  #pragma unroll
  for (int i = 0; i < 8; i++) nz |= ei[2*(tid*8 + i) + 1];
  s[tid] = cnt; t[tid] = nz; __syncthreads();
  for (int o = 128; o > 0; o >>= 1){
    if (tid < o){ s[tid] += s[tid+o]; t[tid] |= t[tid+o]; }
    __syncthreads();
  }
  if (tid == 0){
    *flag = (s[0] >= 3000) ? 1 : 0;
    *eflag = (t[0] == 0) ? 1 : 0;
  }
}

// ---------------- CSR build ----------------
__global__ __launch_bounds__(256) void k_count(const int* __restrict__ ei,
    int* __restrict__ cnt, const int* __restrict__ eflag){
  int i64 = *eflag;
  int e = blockIdx.x*256 + threadIdx.x;
  if (e < N_EDGES) atomicAdd(&cnt[edst(ei, e, i64)], 1);
}

__global__ __launch_bounds__(1024) void k_scan1(const int* __restrict__ cnt,
    int* __restrict__ rowptr, int* __restrict__ bsum){
  __shared__ int lds[1024];
  int tid = threadIdx.x;
  int i = blockIdx.x*1024 + tid;
  int v = (i < N_NODES) ? cnt[i] : 0;
  lds[tid] = v; __syncthreads();
  for (int off = 1; off < 1024; off <<= 1){
    int t = (tid >= off) ? lds[tid - off] : 0;
    __syncthreads();
    lds[tid] += t;
    __syncthreads();
  }
  if (i < N_NODES) rowptr[i] = lds[tid] - v;
  if (tid == 1023) bsum[blockIdx.x] = lds[1023];
}

__global__ __launch_bounds__(128) void k_scan2(int* __restrict__ bsum, int* __restrict__ rowptr){
  __shared__ int lds[128];
  int tid = threadIdx.x;
  int v = (tid < 98) ? bsum[tid] : 0;
  lds[tid] = v; __syncthreads();
  for (int off = 1; off < 128; off <<= 1){
    int t = (tid >= off) ? lds[tid - off] : 0;
    __syncthreads();
    lds[tid] += t;
    __syncthreads();
  }
  if (tid < 98) bsum[tid] = lds[tid] - v;
  if (tid == 127) rowptr[N_NODES] = lds[127];
}

__global__ __launch_bounds__(1024) void k_scan3(int* __restrict__ rowptr,
    int* __restrict__ cursor, const int* __restrict__ bsum){
  int i = blockIdx.x*1024 + threadIdx.x;
  if (i < N_NODES){
    int r = rowptr[i] + bsum[blockIdx.x];
    rowptr[i] = r;
    cursor[i] = r;
  }
}

__global__ __launch_bounds__(256) void k_fill(const int* __restrict__ ei,
    int* __restrict__ cursor, unsigned short* __restrict__ c16,
    unsigned char* __restrict__ c8, const int* __restrict__ eflag){
  int i64 = *eflag;
  int e = blockIdx.x*256 + threadIdx.x;
  if (e < N_EDGES){
    int d = edst(ei, e, i64);
    int p = atomicAdd(&cursor[d], 1);
    int s = esrc(ei, e, i64);
    c16[p] = (unsigned short)(s & 0xffff);
    c8[p]  = (unsigned char)(s >> 16);
  }
}

// ---------------- param prep: split+swizzle weights (padded cols), small params fp32 --
// entry layout per GEMM: [(kb*NTcols + n)*32 + kk]
// qkv  (l,g): (l*2+g)*13824, NTcols=144, kb<3      total 276480
// oproj  l:   276480 + l*12288, NTcols=128, kb<3   total 122880  (cols 80..127 zero)
// ffn1   l:   399360 + l*18432, NTcols=192, kb<3   total 184320  (cols 160..191 zero)
// ffn2   l:   583680 + l*20480, NTcols=128, kb<5   total 204800  (cols 80..127 zero)
// -> 788480 weight elements; params at +788480 (8144 floats)
__global__ __launch_bounds__(256) void k_prep(
    const void* Wq, const void* Wk, const void* Wv, const void* Wo,
    const void* W1, const void* W2, const void* bo, const void* b1,
    const void* b2, const void* We, const void* be,
    const void* Wr0, const void* br0, const void* Wr1, const void* br1,
    const void* Wr2, const void* br2,
    short* __restrict__ whi, short* __restrict__ wlo,
    float* __restrict__ pfS, const int* __restrict__ flagp){
  const int isbf = *flagp;
  int idx = blockIdx.x*256 + threadIdx.x;
  if (idx < 788480){
    float val = 0.f;
    if (idx < 276480){
      int l = idx / 27648; int r = idx % 27648;
      int g = r / 13824; int r2 = r % 13824;
      int kb = r2 / 4608; int r3 = r2 % 4608;
      int n144 = r3 / 32; int kk = r3 % 32;
      int sec = n144 / 48; int n = n144 % 48;
      int k = kb*32 + kk;
      if (k < 80 && n < 40){
        const void* src = (sec == 0) ? Wq : (sec == 1) ? Wk : Wv;
        val = ldf(src, (long)l*6400 + k*80 + g*40 + n, isbf);
      }
    } else if (idx < 399360){
      int r = idx - 276480;
      int l = r / 12288; int r2 = r % 12288;
      int kb = r2 / 4096; int n = (r2 % 4096) / 32; int kk = r2 % 32;
      int k = kb*32 + kk;
      if (k < 80 && n < 80) val = ldf(Wo, (long)l*6400 + k*80 + n, isbf);
    } else if (idx < 583680){
      int r = idx - 399360;
      int l = r / 18432; int r2 = r % 18432;
      int kb = r2 / 6144; int n = (r2 % 6144) / 32; int kk = r2 % 32;
      int k = kb*32 + kk;
      if (k < 80 && n < 160) val = ldf(W1, (long)l*12800 + k*160 + n, isbf);
    } else {
      int r = idx - 583680;
      int l = r / 20480; int r2 = r % 20480;
      int kb = r2 / 4096; int n = (r2 % 4096) / 32; int kk = r2 % 32;
      int k = kb*32 + kk;   // < 160 always
      if (n < 80) val = ldf(W2, (long)l*12800 + k*80 + n, isbf);
    }
    union{float f; unsigned u;} t; t.f = val;
    unsigned hu = t.u & 0xffff0000u;
    whi[idx] = (short)(hu >> 16);
    union{unsigned u; float f;} hf; hf.u = hu;
    union{float f; unsigned u;} t2; t2.f = val - hf.f;
    wlo[idx] = (short)(t2.u >> 16);
    return;
  }
  int p = idx - 788480;
  if (p < 8144){
    float v;
    if      (p < 800)  v = ldf(bo,  p,        isbf);
    else if (p < 2400) v = ldf(b1,  p-800,    isbf);
    else if (p < 3200) v = ldf(b2,  p-2400,   isbf);
    else if (p < 3920) v = ldf(We,  p-3200,   isbf);
    else if (p < 4000) v = ldf(be,  p-3920,   isbf);
    else if (p < 7200) v = ldf(Wr0, p-4000,   isbf);
    else if (p < 7240) v = ldf(br0, p-7200,   isbf);
    else if (p < 8040) v = ldf(Wr1, p-7240,   isbf);
    else if (p < 8060) v = ldf(br1, p-8040,   isbf);
    else if (p < 8140) v = ldf(Wr2, p-8060,   isbf);
    else               v = ldf(br2, p-8140,   isbf);
    pfS[p] = v;
  }
}

// ---------------- embedding ----------------
__global__ __launch_bounds__(256) void k_embed(const void* __restrict__ x,
    const float* __restrict__ WeF, const float* __restrict__ beF,
    float* __restrict__ h, const int* __restrict__ flagp){
  __shared__ float Wl[720];
  __shared__ float bl[80];
  const int isbf = *flagp;
  int tid = threadIdx.x;
  for (int i = tid; i < 720; i += 256) Wl[i] = WeF[i];
  if (tid < 80) bl[tid] = beF[tid];
  __syncthreads();
  long idx = (long)blockIdx.x*256 + tid;
  int n = (int)(idx / 80); int c = (int)(idx - (long)n*80);
  float s = bl[c];
  #pragma unroll
  for (int k = 0; k < 9; k++) s = fmaf(ldf(x, (long)n*9 + k, isbf), Wl[k*80 + c], s);
  h[idx] = s;
}

// ---------------- QKV GEMM: row-blocked (R=2), split-bf16 MFMA ----------------
__global__ __launch_bounds__(256) void k_qkv(
    const float* __restrict__ h,
    const short* __restrict__ Whi, const short* __restrict__ Wlo,
    float* __restrict__ outQ, long slot){
  const int tid  = threadIdx.x;
  const int w    = tid >> 6;
  const int lane = tid & 63;
  const int m16  = lane & 15;
  const int q    = lane >> 4;
  const int rowbase = blockIdx.x*128 + w*32;

  f32x4 acc[2][9];
  #pragma unroll
  for (int rg = 0; rg < 2; rg++)
    #pragma unroll
    for (int t = 0; t < 9; t++) acc[rg][t] = (f32x4){0.f,0.f,0.f,0.f};

  #pragma unroll
  for (int kb = 0; kb < 3; kb++){
    int k0 = kb*32 + q*8;
    short8 ahi[2], alo[2];
    #pragma unroll
    for (int rg = 0; rg < 2; rg++){
      ahi[rg] = (short8)0; alo[rg] = (short8)0;
      if (k0 < 80){
        int grow = rowbase + rg*16 + m16;
        if (grow >= N_NODES) grow = N_NODES-1;
        split8(h + (long)grow*80 + k0, ahi[rg], alo[rg]);
      }
    }
    #pragma unroll
    for (int t = 0; t < 9; t++){
      long wi = ((long)(kb*144 + t*16 + m16))*32 + q*8;
      short8 bhi = *(const short8*)(Whi + wi);
      short8 blo = *(const short8*)(Wlo + wi);
      #pragma unroll
      for (int rg = 0; rg < 2; rg++){
        acc[rg][t] = __builtin_amdgcn_mfma_f32_16x16x32_bf16(alo[rg], bhi, acc[rg][t], 0, 0, 0);
        acc[rg][t] = __builtin_amdgcn_mfma_f32_16x16x32_bf16(ahi[rg], blo, acc[rg][t], 0, 0, 0);
        acc[rg][t] = __builtin_amdgcn_mfma_f32_16x16x32_bf16(ahi[rg], bhi, acc[rg][t], 0, 0, 0);
      }
    }
  }
  #pragma unroll
  for (int t = 0; t < 9; t++){
    int sec = t/3; int c = (t%3)*16 + m16;
    if (c < 40){
      float* ob = outQ + (long)sec*slot;
      #pragma unroll
      for (int rg = 0; rg < 2; rg++){
        #pragma unroll
        for (int r2 = 0; r2 < 4; r2++){
          int grow = rowbase + rg*16 + q*4 + r2;
          if (grow < N_NODES) ob[(long)grow*40 + c] = acc[rg][t][r2];
        }
      }
    }
  }
}

// ---------------- fused post-attention: oproj + FFN1 + FFN2 (no scratch) ----------
// block = 64 rows. Wave-uniform padded tiles: oproj 8 (5 real), ffn1 12 (10 real),
// ffn2 8 (5 real). ALL loop bounds compile-time -> accs stay in registers.
__global__ __launch_bounds__(256,2) void k_post(
    const float* __restrict__ attn0, const float* __restrict__ attn1,
    float* __restrict__ h,
    const short* __restrict__ WhiO, const short* __restrict__ WloO,
    const short* __restrict__ Whi1, const short* __restrict__ Wlo1,
    const short* __restrict__ Whi2, const short* __restrict__ Wlo2,
    const float* __restrict__ bo, const float* __restrict__ b1,
    const float* __restrict__ b2){
  __shared__ float hs[64*84];        // h_new, row stride 84
  __shared__ short t_hi[64*168];     // relu(ffn1) split-hi, row stride 168
  __shared__ short t_lo[64*168];
  const int tid  = threadIdx.x;
  const int w    = tid >> 6;
  const int lane = tid & 63;
  const int m16  = lane & 15;
  const int q    = lane >> 4;
  const int row0 = blockIdx.x*64;

  // ---- stage 1: oproj — tiles w and w+4 of 8 (cols >= 80 are zero-weight phantoms)
  {
    f32x4 acc[4][2];
    #pragma unroll
    for (int rg = 0; rg < 4; rg++)
      #pragma unroll
      for (int it = 0; it < 2; it++) acc[rg][it] = (f32x4){0.f,0.f,0.f,0.f};
    #pragma unroll
    for (int kb = 0; kb < 3; kb++){
      int k0 = kb*32 + q*8;
      short8 ahi[4], alo[4];
      #pragma unroll
      for (int rg = 0; rg < 4; rg++){
        ahi[rg] = (short8)0; alo[rg] = (short8)0;
        if (k0 < 80){
          int grow = row0 + rg*16 + m16;
          if (grow >= N_NODES) grow = N_NODES-1;
          const float* p = (k0 < 40) ? attn0 + (long)grow*40 + k0
                                     : attn1 + (long)grow*40 + (k0-40);
          split8(p, ahi[rg], alo[rg]);
        }
      }
      #pragma unroll
      for (int it = 0; it < 2; it++){
        int t = w + it*4;
        long wi = ((long)(kb*128 + t*16 + m16))*32 + q*8;
        short8 bhi = *(const short8*)(WhiO + wi);
        short8 blo = *(const short8*)(WloO + wi);
        #pragma unroll
        for (int rg = 0; rg < 4; rg++){
          acc[rg][it] = __builtin_amdgcn_mfma_f32_16x16x32_bf16(alo[rg], bhi, acc[rg][it], 0, 0, 0);
          acc[rg][it] = __builtin_amdgcn_mfma_f32_16x16x32_bf16(ahi[rg], blo, acc[rg][it], 0, 0, 0);
          acc[rg][it] = __builtin_amdgcn_mfma_f32_16x16x32_bf16(ahi[rg], bhi, acc[rg][it], 0, 0, 0);
        }
      }
    }
    #pragma unroll
    for (int it = 0; it < 2; it++){
      int t = w + it*4;
      if (t < 5){                       // wave-uniform guard, real cols only
        int col = t*16 + m16;
        float bb = bo[col];
        #pragma unroll
        for (int rg = 0; rg < 4; rg++){
          #pragma unroll
          for (int r2 = 0; r2 < 4; r2++){
            int rloc = rg*16 + q*4 + r2;
            int grow = row0 + rloc;
            float resid = (grow < N_NODES) ? h[(long)grow*80 + col] : 0.f;
            hs[rloc*84 + col] = acc[rg][it][r2] + bb + resid;
          }
        }
      }
    }
  }
  __syncthreads();

  // ---- stage 2: ffn1 — tiles w, w+4, w+8 of 12 (cols >= 160 phantoms)
  {
    f32x4 acc[4][3];
    #pragma unroll
    for (int rg = 0; rg < 4; rg++)
      #pragma unroll
      for (int it = 0; it < 3; it++) acc[rg][it] = (f32x4){0.f,0.f,0.f,0.f};
    #pragma unroll
    for (int kb = 0; kb < 3; kb++){
      int k0 = kb*32 + q*8;
      short8 ahi[4], alo[4];
      #pragma unroll
      for (int rg = 0; rg < 4; rg++){
        ahi[rg] = (short8)0; alo[rg] = (short8)0;
        if (k0 < 80){
          int rloc = rg*16 + m16;
          split8(&hs[rloc*84 + k0], ahi[rg], alo[rg]);
        }
      }
      #pragma unroll
      for (int it = 0; it < 3; it++){
        int t = w + it*4;
        long wi = ((long)(kb*192 + t*16 + m16))*32 + q*8;
        short8 bhi = *(const short8*)(Whi1 + wi);
        short8 blo = *(const short8*)(Wlo1 + wi);
        #pragma unroll
        for (int rg = 0; rg < 4; rg++){
          acc[rg][it] = __builtin_amdgcn_mfma_f32_16x16x32_bf16(alo[rg], bhi, acc[rg][it], 0, 0, 0);
          acc[rg][it] = __builtin_amdgcn_mfma_f32_16x16x32_bf16(ahi[rg], blo, acc[rg][it], 0, 0, 0);
          acc[rg][it] = __builtin_amdgcn_mfma_f32_16x16x32_bf16(ahi[rg], bhi, acc[rg][it], 0, 0, 0);
        }
      }
    }
    #pragma unroll
    for (int it = 0; it < 3; it++){
      int t = w + it*4;
      if (t < 10){
        int col = t*16 + m16;
        float bb = b1[col];
        #pragma unroll
        for (int rg = 0; rg < 4; rg++){
          #pragma unroll
          for (int r2 = 0; r2 < 4; r2++){
            int rloc = rg*16 + q*4 + r2;
            float val = fmaxf(acc[rg][it][r2] + bb, 0.f);
            short hi16, lo16; splitval(val, hi16, lo16);
            t_hi[rloc*168 + col] = hi16;
            t_lo[rloc*168 + col] = lo16;
          }
        }
      }
    }
  }
  __syncthreads();

  // ---- stage 3: ffn2 — K=160 from LDS, tiles w and w+4 of 8 (cols >= 80 phantoms)
  {
    f32x4 acc[4][2];
    #pragma unroll
    for (int rg = 0; rg < 4; rg++)
      #pragma unroll
      for (int it = 0; it < 2; it++) acc[rg][it] = (f32x4){0.f,0.f,0.f,0.f};
    #pragma unroll
    for (int kb = 0; kb < 5; kb++){
      int k0 = kb*32 + q*8;
      short8 ahi[4], alo[4];
      #pragma unroll
      for (int rg = 0; rg < 4; rg++){
        int rloc = rg*16 + m16;
        ahi[rg] = *(const short8*)(&t_hi[rloc*168 + k0]);
        alo[rg] = *(const short8*)(&t_lo[rloc*168 + k0]);
      }
      #pragma unroll
      for (int it = 0; it < 2; it++){
        int t = w + it*4;
        long wi = ((long)(kb*128 + t*16 + m16))*32 + q*8;
        short8 bhi = *(const short8*)(Whi2 + wi);
        short8 blo = *(const short8*)(Wlo2 + wi);
        #pragma unroll
        for (int rg = 0; rg < 4; rg++){
          acc[rg][it] = __builtin_amdgcn_mfma_f32_16x16x32_bf16(alo[rg], bhi, acc[rg][it], 0, 0, 0);
          acc[rg][it] = __builtin_amdgcn_mfma_f32_16x16x32_bf16(ahi[rg], blo, acc[rg][it], 0, 0, 0);
          acc[rg][it] = __builtin_amdgcn_mfma_f32_16x16x32_bf16(ahi[rg], bhi, acc[rg][it], 0, 0, 0);
        }
      }
    }
    #pragma unroll
    for (int it = 0; it < 2; it++){
      int t = w + it*4;
      if (t < 5){
        int col = t*16 + m16;
        float bb = b2[col];
        #pragma unroll
        for (int rg = 0; rg < 4; rg++){
          #pragma unroll
          for (int r2 = 0; r2 < 4; r2++){
            int rloc = rg*16 + q*4 + r2;
            int grow = row0 + rloc;
            if (grow < N_NODES)
              h[(long)grow*80 + col] = acc[rg][it][r2] + bb + hs[rloc*84 + col];
          }
        }
      }
    }
  }
}

// ---------------- edge-softmax attention: wave per node ----------------
__global__ __launch_bounds__(256) void k_attn(
    float* __restrict__ Qg, const float* __restrict__ Kg, const float* __restrict__ Vg,
    const int* __restrict__ rowptr, const unsigned short* __restrict__ c16,
    const unsigned char* __restrict__ c8){
  int n = (blockIdx.x*256 + threadIdx.x) >> 6;
  int lane = threadIdx.x & 63;
  int el = lane >> 2;
  int hh = lane & 3;
  const float* qp = Qg + (long)n*40 + hh*10;
  float qv[10];
  #pragma unroll
  for (int i = 0; i < 5; i++){ float2 t = *(const float2*)(qp + 2*i); qv[2*i]=t.x; qv[2*i+1]=t.y; }
  float acc[10];
  #pragma unroll
  for (int i = 0; i < 10; i++) acc[i] = 0.f;
  float z = 0.f;
  int e0 = rowptr[n], e1 = rowptr[n+1];
  for (int j0 = e0; j0 < e1; j0 += 16){
    int j = j0 + el;
    bool valid = (j < e1);
    int jj = valid ? j : e0;
    int src = (int)c16[jj] | ((int)c8[jj] << 16);
    const float* kp = Kg + (long)src*40 + hh*10;
    const float* vp = Vg + (long)src*40 + hh*10;
    float dot = 0.f;
    #pragma unroll
    for (int i = 0; i < 5; i++){
      float2 kv = *(const float2*)(kp + 2*i);
      dot = fmaf(kv.x, qv[2*i], dot);
      dot = fmaf(kv.y, qv[2*i+1], dot);
    }
    float sc = fminf(fmaxf(dot * 0.31622776601683794f, -5.f), 5.f);
    float s = valid ? __expf(sc) : 0.f;
    z += s;
    #pragma unroll
    for (int i = 0; i < 5; i++){
      float2 vv = *(const float2*)(vp + 2*i);
      acc[2*i]   = fmaf(s, vv.x, acc[2*i]);
      acc[2*i+1] = fmaf(s, vv.y, acc[2*i+1]);
    }
  }
  #pragma unroll
  for (int m = 4; m <= 32; m <<= 1){
    z += __shfl_xor(z, m, 64);
    #pragma unroll
    for (int i = 0; i < 10; i++) acc[i] += __shfl_xor(acc[i], m, 64);
  }
  if (el == 0){
    float inv = 1.f / (z + 1e-6f);
    float* op = Qg + (long)n*40 + hh*10;
    #pragma unroll
    for (int i = 0; i < 5; i++){
      float2 o; o.x = acc[2*i]*inv; o.y = acc[2*i+1]*inv;
      *(float2*)(op + 2*i) = o;
    }
  }
}

// ---------------- MLP readout 80->40->20->4, fp32 output ----------------
__global__ __launch_bounds__(256) void k_readout(const float* __restrict__ h,
    const float* __restrict__ roF,
    float* __restrict__ out){
  __shared__ float w0[3200], w1[800], w2[80], bb0[40], bb1[20], bb2[4];
  int tid = threadIdx.x;
  for (int i = tid; i < 3200; i += 256) w0[i] = roF[i];
  for (int i = tid; i < 800;  i += 256) w1[i] = roF[3240 + i];
  if (tid < 80) w2[tid]  = roF[4060 + tid];
  if (tid < 40) bb0[tid] = roF[3200 + tid];
  if (tid < 20) bb1[tid] = roF[4040 + tid];
  if (tid < 4)  bb2[tid] = roF[4140 + tid];
  __syncthreads();
  int n = blockIdx.x*256 + tid;
  if (n >= N_NODES) return;
  float t0[40];
  #pragma unroll
  for (int c = 0; c < 40; c++) t0[c] = bb0[c];
  for (int k4 = 0; k4 < 20; k4++){
    float4 hv = *(const float4*)(h + (size_t)n*80 + k4*4);
    float hx[4] = {hv.x, hv.y, hv.z, hv.w};
    #pragma unroll
    for (int j = 0; j < 4; j++){
      int k = k4*4 + j;
      #pragma unroll
      for (int c = 0; c < 40; c++) t0[c] = fmaf(hx[j], w0[k*40 + c], t0[c]);
    }
  }
  float t1[20];
  #pragma unroll
  for (int c = 0; c < 20; c++) t1[c] = bb1[c];
  for (int k = 0; k < 40; k++){
    float a = fmaxf(t0[k], 0.f);
    #pragma unroll
    for (int c = 0; c < 20; c++) t1[c] = fmaf(a, w1[k*20 + c], t1[c]);
  }
  float o[4];
  #pragma unroll
  for (int c = 0; c < 4; c++) o[c] = bb2[c];
  for (int k = 0; k < 20; k++){
    float a = fmaxf(t1[k], 0.f);
    #pragma unroll
    for (int c = 0; c < 4; c++) o[c] = fmaf(a, w2[k*4 + c], o[c]);
  }
  #pragma unroll
  for (int c = 0; c < 4; c++) out[n*4 + c] = o[c];
}

// ---------------- launch ----------------
extern "C" void kernel_launch(void* const* d_in, const int* in_sizes, int n_in,
                              void* d_out, int out_size, void* d_ws, size_t ws_size,
                              hipStream_t stream){
  const void* x   = d_in[0];
  const int*  ei  = (const int*)d_in[1];
  const void* We  = d_in[2];
  const void* be  = d_in[3];
  const void* Wq  = d_in[4];
  const void* Wk  = d_in[5];
  const void* Wv  = d_in[6];
  const void* Wo  = d_in[7];
  const void* bo  = d_in[8];
  const void* W1  = d_in[9];
  const void* b1  = d_in[10];
  const void* W2  = d_in[11];
  const void* b2  = d_in[12];
  const void* Wr0 = d_in[13];
  const void* br0 = d_in[14];
  const void* Wr1 = d_in[15];
  const void* br1 = d_in[16];
  const void* Wr2 = d_in[17];
  const void* br2 = d_in[18];

  char* ws = (char*)d_ws;
  int*   flag   = (int*)(ws + 0);
  int*   eflag  = (int*)(ws + 4);
  int*   bsum   = (int*)(ws + 64);                 // 98 ints
  float* h      = (float*)(ws + 1024);             // 32,000,000
  float* B      = (float*)(ws + 32001024);         // 64,000,000 (4 slots x 4e6 floats)
  short* Whi    = (short*)(ws + 96001024);         // 788480*2 = 1,576,960
  short* Wlo    = (short*)(ws + 97577984);         // 1,576,960
  float* pfS    = (float*)(ws + 99154944);         // 32,576
  int*   rowptr = (int*)(ws + 99187520);           // 400,004
  unsigned short* c16 = (unsigned short*)(ws + 99587524);  // 2,000,000
  unsigned char*  c8  = (unsigned char*)(ws + 101587524);  // 1,000,000 -> end 102,587,524
  int*   cursor = (int*)B;                         // aliases B (dead before layers)
  float* out    = (float*)d_out;

  const long SLOT = 4000000;
  const float* boF = pfS + 0;
  const float* b1F = pfS + 800;
  const float* b2F = pfS + 2400;
  const float* WeF = pfS + 3200;
  const float* beF = pfS + 3920;
  const float* roF = pfS + 4000;

  k_detect<<<1, 256, 0, stream>>>((const unsigned*)x, ei, flag, eflag);
  hipMemsetAsync(cursor, 0, N_NODES*sizeof(int), stream);
  k_count<<<(N_EDGES+255)/256, 256, 0, stream>>>(ei, cursor, eflag);
  k_scan1<<<98, 1024, 0, stream>>>(cursor, rowptr, bsum);
  k_scan2<<<1, 128, 0, stream>>>(bsum, rowptr);
  k_scan3<<<98, 1024, 0, stream>>>(rowptr, cursor, bsum);
  k_fill<<<(N_EDGES+255)/256, 256, 0, stream>>>(ei, cursor, c16, c8, eflag);
  k_prep<<<3112, 256, 0, stream>>>(Wq, Wk, Wv, Wo, W1, W2, bo, b1, b2, We, be,
                                   Wr0, br0, Wr1, br1, Wr2, br2, Whi, Wlo, pfS, flag);
  k_embed<<<(N_NODES*80)/256, 256, 0, stream>>>(x, WeF, beF, h, flag);

  const int qblk = (N_NODES + 127) / 128;   // 782
  const int pblk = (N_NODES + 63) / 64;     // 1563
  const int ablk = N_NODES / 4;             // 25000
  for (int l = 0; l < NLAYERS; l++){
    for (int g = 0; g < 2; g++){
      k_qkv<<<qblk, 256, 0, stream>>>(
          h, Whi + (l*2+g)*13824, Wlo + (l*2+g)*13824, B + g*SLOT, SLOT);
      k_attn<<<ablk, 256, 0, stream>>>(
          B + g*SLOT, B + (g+1)*SLOT, B + (g+2)*SLOT, rowptr, c16, c8);
    }
    k_post<<<pblk, 256, 0, stream>>>(
        B, B + SLOT, h,
        Whi + 276480 + l*12288, Wlo + 276480 + l*12288,
        Whi + 399360 + l*18432, Wlo + 399360 + l*18432,
        Whi + 583680 + l*20480, Wlo + 583680 + l*20480,
        boF + l*80, b1F + l*160, b2F + l*80);
  }
  k_readout<<<(N_NODES+255)/256, 256, 0, stream>>>(h, roF, out);
}

// Round 11
// 2690.167 us; speedup vs baseline: 1.3704x; 1.1487x over previous
//
#include <hip/hip_runtime.h>
#include <hip/hip_bf16.h>

#define N_NODES 100000
#define N_EDGES 1000000
#define NLAYERS 10

typedef __hip_bfloat16 bf16;
typedef __attribute__((ext_vector_type(8))) short short8;
typedef __attribute__((ext_vector_type(4))) float f32x4;

// flag-aware float load: isbf=1 -> treat p as bf16 array, else fp32
__device__ __forceinline__ float ldf(const void* p, long i, int isbf){
  if (isbf){
    unsigned short u = ((const unsigned short*)p)[i];
    union{unsigned u; float f;} c; c.u = ((unsigned)u) << 16; return c.f;
  }
  return ((const float*)p)[i];
}

__device__ __forceinline__ int esrc(const int* ei, int e, int i64){
  return i64 ? ei[2*e] : ei[e];
}
__device__ __forceinline__ int edst(const int* ei, int e, int i64){
  return i64 ? ei[2*N_EDGES + 2*e] : ei[N_EDGES + e];
}

// split fp32 -> bf16 hi (truncate) + bf16 lo (residual)
__device__ __forceinline__ void split8(const float* p, short8& hi, short8& lo){
  float4 a = *(const float4*)p; float4 b = *(const float4*)(p+4);
  float v[8] = {a.x,a.y,a.z,a.w,b.x,b.y,b.z,b.w};
  #pragma unroll
  for (int i = 0; i < 8; i++){
    union{float f; unsigned u;} t; t.f = v[i];
    unsigned hu = t.u & 0xffff0000u;
    hi[i] = (short)(hu >> 16);
    union{unsigned u; float f;} hf; hf.u = hu;
    union{float f; unsigned u;} t2; t2.f = v[i] - hf.f;
    lo[i] = (short)(t2.u >> 16);
  }
}

__device__ __forceinline__ void splitval(float val, short& hi, short& lo){
  union{float f; unsigned u;} t; t.f = val;
  unsigned hu = t.u & 0xffff0000u;
  hi = (short)(hu >> 16);
  union{unsigned u; float f;} hf; hf.u = hu;
  union{float f; unsigned u;} t2; t2.f = val - hf.f;
  lo = (short)(t2.u >> 16);
}

// ---------------- dtype detection (parallel) ----------------
__global__ __launch_bounds__(256) void k_detect(const unsigned* __restrict__ xw,
                                                const int* __restrict__ ei,
                                                int* __restrict__ flag,
                                                int* __restrict__ eflag){
  __shared__ int s[256];
  __shared__ int t[256];
  int tid = threadIdx.x;
  int cnt = 0;
  #pragma unroll
  for (int i = 0; i < 16; i++){
    unsigned u = xw[tid*16 + i];
    unsigned lo = u & 0xffffu;
    unsigned e = (lo >> 7) & 0xff;
    if ((e >= 96 && e <= 150) || lo == 0) cnt++;
  }
  int nz = 0;
  #pragma unroll
  for (int i = 0; i < 8; i++) nz |= ei[2*(tid*8 + i) + 1];
  s[tid] = cnt; t[tid] = nz; __syncthreads();
  for (int o = 128; o > 0; o >>= 1){
    if (tid < o){ s[tid] += s[tid+o]; t[tid] |= t[tid+o]; }
    __syncthreads();
  }
  if (tid == 0){
    *flag = (s[0] >= 3000) ? 1 : 0;
    *eflag = (t[0] == 0) ? 1 : 0;
  }
}

// ---------------- CSR build ----------------
__global__ __launch_bounds__(256) void k_count(const int* __restrict__ ei,
    int* __restrict__ cnt, const int* __restrict__ eflag){
  int i64 = *eflag;
  int e = blockIdx.x*256 + threadIdx.x;
  if (e < N_EDGES) atomicAdd(&cnt[edst(ei, e, i64)], 1);
}

__global__ __launch_bounds__(1024) void k_scan1(const int* __restrict__ cnt,
    int* __restrict__ rowptr, int* __restrict__ bsum){
  __shared__ int lds[1024];
  int tid = threadIdx.x;
  int i = blockIdx.x*1024 + tid;
  int v = (i < N_NODES) ? cnt[i] : 0;
  lds[tid] = v; __syncthreads();
  for (int off = 1; off < 1024; off <<= 1){
    int t = (tid >= off) ? lds[tid - off] : 0;
    __syncthreads();
    lds[tid] += t;
    __syncthreads();
  }
  if (i < N_NODES) rowptr[i] = lds[tid] - v;
  if (tid == 1023) bsum[blockIdx.x] = lds[1023];
}

__global__ __launch_bounds__(128) void k_scan2(int* __restrict__ bsum, int* __restrict__ rowptr){
  __shared__ int lds[128];
  int tid = threadIdx.x;
  int v = (tid < 98) ? bsum[tid] : 0;
  lds[tid] = v; __syncthreads();
  for (int off = 1; off < 128; off <<= 1){
    int t = (tid >= off) ? lds[tid - off] : 0;
    __syncthreads();
    lds[tid] += t;
    __syncthreads();
  }
  if (tid < 98) bsum[tid] = lds[tid] - v;
  if (tid == 127) rowptr[N_NODES] = lds[127];
}

__global__ __launch_bounds__(1024) void k_scan3(int* __restrict__ rowptr,
    int* __restrict__ cursor, const int* __restrict__ bsum){
  int i = blockIdx.x*1024 + threadIdx.x;
  if (i < N_NODES){
    int r = rowptr[i] + bsum[blockIdx.x];
    rowptr[i] = r;
    cursor[i] = r;
  }
}

__global__ __launch_bounds__(256) void k_fill(const int* __restrict__ ei,
    int* __restrict__ cursor, unsigned short* __restrict__ c16,
    unsigned char* __restrict__ c8, const int* __restrict__ eflag){
  int i64 = *eflag;
  int e = blockIdx.x*256 + threadIdx.x;
  if (e < N_EDGES){
    int d = edst(ei, e, i64);
    int p = atomicAdd(&cursor[d], 1);
    int s = esrc(ei, e, i64);
    c16[p] = (unsigned short)(s & 0xffff);
    c8[p]  = (unsigned char)(s >> 16);
  }
}

// ---------------- param prep: split+swizzle weights (padded cols), small params fp32 --
// entry layout per GEMM: [(kb*NTcols + n)*32 + kk]
// qkv  (l,g): (l*2+g)*13824, NTcols=144, kb<3      total 276480
// oproj  l:   276480 + l*12288, NTcols=128, kb<3   total 122880  (cols 80..127 zero)
// ffn1   l:   399360 + l*18432, NTcols=192, kb<3   total 184320  (cols 160..191 zero)
// ffn2   l:   583680 + l*20480, NTcols=128, kb<5   total 204800  (cols 80..127 zero)
// -> 788480 weight elements; params at +788480 (8144 floats)
__global__ __launch_bounds__(256) void k_prep(
    const void* Wq, const void* Wk, const void* Wv, const void* Wo,
    const void* W1, const void* W2, const void* bo, const void* b1,
    const void* b2, const void* We, const void* be,
    const void* Wr0, const void* br0, const void* Wr1, const void* br1,
    const void* Wr2, const void* br2,
    short* __restrict__ whi, short* __restrict__ wlo,
    float* __restrict__ pfS, const int* __restrict__ flagp){
  const int isbf = *flagp;
  int idx = blockIdx.x*256 + threadIdx.x;
  if (idx < 788480){
    float val = 0.f;
    if (idx < 276480){
      int l = idx / 27648; int r = idx % 27648;
      int g = r / 13824; int r2 = r % 13824;
      int kb = r2 / 4608; int r3 = r2 % 4608;
      int n144 = r3 / 32; int kk = r3 % 32;
      int sec = n144 / 48; int n = n144 % 48;
      int k = kb*32 + kk;
      if (k < 80 && n < 40){
        const void* src = (sec == 0) ? Wq : (sec == 1) ? Wk : Wv;
        val = ldf(src, (long)l*6400 + k*80 + g*40 + n, isbf);
      }
    } else if (idx < 399360){
      int r = idx - 276480;
      int l = r / 12288; int r2 = r % 12288;
      int kb = r2 / 4096; int n = (r2 % 4096) / 32; int kk = r2 % 32;
      int k = kb*32 + kk;
      if (k < 80 && n < 80) val = ldf(Wo, (long)l*6400 + k*80 + n, isbf);
    } else if (idx < 583680){
      int r = idx - 399360;
      int l = r / 18432; int r2 = r % 18432;
      int kb = r2 / 6144; int n = (r2 % 6144) / 32; int kk = r2 % 32;
      int k = kb*32 + kk;
      if (k < 80 && n < 160) val = ldf(W1, (long)l*12800 + k*160 + n, isbf);
    } else {
      int r = idx - 583680;
      int l = r / 20480; int r2 = r % 20480;
      int kb = r2 / 4096; int n = (r2 % 4096) / 32; int kk = r2 % 32;
      int k = kb*32 + kk;   // < 160 always
      if (n < 80) val = ldf(W2, (long)l*12800 + k*80 + n, isbf);
    }
    union{float f; unsigned u;} t; t.f = val;
    unsigned hu = t.u & 0xffff0000u;
    whi[idx] = (short)(hu >> 16);
    union{unsigned u; float f;} hf; hf.u = hu;
    union{float f; unsigned u;} t2; t2.f = val - hf.f;
    wlo[idx] = (short)(t2.u >> 16);
    return;
  }
  int p = idx - 788480;
  if (p < 8144){
    float v;
    if      (p < 800)  v = ldf(bo,  p,        isbf);
    else if (p < 2400) v = ldf(b1,  p-800,    isbf);
    else if (p < 3200) v = ldf(b2,  p-2400,   isbf);
    else if (p < 3920) v = ldf(We,  p-3200,   isbf);
    else if (p < 4000) v = ldf(be,  p-3920,   isbf);
    else if (p < 7200) v = ldf(Wr0, p-4000,   isbf);
    else if (p < 7240) v = ldf(br0, p-7200,   isbf);
    else if (p < 8040) v = ldf(Wr1, p-7240,   isbf);
    else if (p < 8060) v = ldf(br1, p-8040,   isbf);
    else if (p < 8140) v = ldf(Wr2, p-8060,   isbf);
    else               v = ldf(br2, p-8140,   isbf);
    pfS[p] = v;
  }
}

// ---------------- embedding ----------------
__global__ __launch_bounds__(256) void k_embed(const void* __restrict__ x,
    const float* __restrict__ WeF, const float* __restrict__ beF,
    float* __restrict__ h, const int* __restrict__ flagp){
  __shared__ float Wl[720];
  __shared__ float bl[80];
  const int isbf = *flagp;
  int tid = threadIdx.x;
  for (int i = tid; i < 720; i += 256) Wl[i] = WeF[i];
  if (tid < 80) bl[tid] = beF[tid];
  __syncthreads();
  long idx = (long)blockIdx.x*256 + tid;
  int n = (int)(idx / 80); int c = (int)(idx - (long)n*80);
  float s = bl[c];
  #pragma unroll
  for (int k = 0; k < 9; k++) s = fmaf(ldf(x, (long)n*9 + k, isbf), Wl[k*80 + c], s);
  h[idx] = s;
}

// ---------------- QKV GEMM: row-blocked (R=2), split-bf16 MFMA ----------------
// outputs: Q -> Qo[row*40+c]; K -> KV[row*80+c]; V -> KV[row*80+40+c] (interleaved)
__global__ __launch_bounds__(256) void k_qkv(
    const float* __restrict__ h,
    const short* __restrict__ Whi, const short* __restrict__ Wlo,
    float* __restrict__ Qo, float* __restrict__ KV){
  const int tid  = threadIdx.x;
  const int w    = tid >> 6;
  const int lane = tid & 63;
  const int m16  = lane & 15;
  const int q    = lane >> 4;
  const int rowbase = blockIdx.x*128 + w*32;

  f32x4 acc[2][9];
  #pragma unroll
  for (int rg = 0; rg < 2; rg++)
    #pragma unroll
    for (int t = 0; t < 9; t++) acc[rg][t] = (f32x4){0.f,0.f,0.f,0.f};

  #pragma unroll
  for (int kb = 0; kb < 3; kb++){
    int k0 = kb*32 + q*8;
    short8 ahi[2], alo[2];
    #pragma unroll
    for (int rg = 0; rg < 2; rg++){
      ahi[rg] = (short8)0; alo[rg] = (short8)0;
      if (k0 < 80){
        int grow = rowbase + rg*16 + m16;
        if (grow >= N_NODES) grow = N_NODES-1;
        split8(h + (long)grow*80 + k0, ahi[rg], alo[rg]);
      }
    }
    #pragma unroll
    for (int t = 0; t < 9; t++){
      long wi = ((long)(kb*144 + t*16 + m16))*32 + q*8;
      short8 bhi = *(const short8*)(Whi + wi);
      short8 blo = *(const short8*)(Wlo + wi);
      #pragma unroll
      for (int rg = 0; rg < 2; rg++){
        acc[rg][t] = __builtin_amdgcn_mfma_f32_16x16x32_bf16(alo[rg], bhi, acc[rg][t], 0, 0, 0);
        acc[rg][t] = __builtin_amdgcn_mfma_f32_16x16x32_bf16(ahi[rg], blo, acc[rg][t], 0, 0, 0);
        acc[rg][t] = __builtin_amdgcn_mfma_f32_16x16x32_bf16(ahi[rg], bhi, acc[rg][t], 0, 0, 0);
      }
    }
  }
  #pragma unroll
  for (int t = 0; t < 9; t++){
    int sec = t/3; int c = (t%3)*16 + m16;
    if (c < 40){
      #pragma unroll
      for (int rg = 0; rg < 2; rg++){
        #pragma unroll
        for (int r2 = 0; r2 < 4; r2++){
          int grow = rowbase + rg*16 + q*4 + r2;
          if (grow < N_NODES){
            if (sec == 0)      Qo[(long)grow*40 + c]      = acc[rg][t][r2];
            else if (sec == 1) KV[(long)grow*80 + c]      = acc[rg][t][r2];
            else               KV[(long)grow*80 + 40 + c] = acc[rg][t][r2];
          }
        }
      }
    }
  }
}

// ---------------- fused post-attention: oproj + FFN1 + FFN2 (32-row blocks) --------
// block = 32 rows, 4 waves split output col-tiles; LDS 32.25 KB -> 4 blocks/CU.
__global__ __launch_bounds__(256,4) void k_post(
    const float* __restrict__ attn0, const float* __restrict__ attn1,
    float* __restrict__ h,
    const short* __restrict__ WhiO, const short* __restrict__ WloO,
    const short* __restrict__ Whi1, const short* __restrict__ Wlo1,
    const short* __restrict__ Whi2, const short* __restrict__ Wlo2,
    const float* __restrict__ bo, const float* __restrict__ b1,
    const float* __restrict__ b2){
  __shared__ float hs[32*84];        // h_new, row stride 84
  __shared__ short t_hi[32*168];     // relu(ffn1) split-hi, row stride 168
  __shared__ short t_lo[32*168];
  const int tid  = threadIdx.x;
  const int w    = tid >> 6;
  const int lane = tid & 63;
  const int m16  = lane & 15;
  const int q    = lane >> 4;
  const int row0 = blockIdx.x*32;

  // ---- stage 1: oproj — tiles w and w+4 of 8 (cols >= 80 zero-weight phantoms)
  {
    f32x4 acc[2][2];
    #pragma unroll
    for (int rg = 0; rg < 2; rg++)
      #pragma unroll
      for (int it = 0; it < 2; it++) acc[rg][it] = (f32x4){0.f,0.f,0.f,0.f};
    #pragma unroll
    for (int kb = 0; kb < 3; kb++){
      int k0 = kb*32 + q*8;
      short8 ahi[2], alo[2];
      #pragma unroll
      for (int rg = 0; rg < 2; rg++){
        ahi[rg] = (short8)0; alo[rg] = (short8)0;
        if (k0 < 80){
          int grow = row0 + rg*16 + m16;
          if (grow >= N_NODES) grow = N_NODES-1;
          const float* p = (k0 < 40) ? attn0 + (long)grow*40 + k0
                                     : attn1 + (long)grow*40 + (k0-40);
          split8(p, ahi[rg], alo[rg]);
        }
      }
      #pragma unroll
      for (int it = 0; it < 2; it++){
        int t = w + it*4;
        long wi = ((long)(kb*128 + t*16 + m16))*32 + q*8;
        short8 bhi = *(const short8*)(WhiO + wi);
        short8 blo = *(const short8*)(WloO + wi);
        #pragma unroll
        for (int rg = 0; rg < 2; rg++){
          acc[rg][it] = __builtin_amdgcn_mfma_f32_16x16x32_bf16(alo[rg], bhi, acc[rg][it], 0, 0, 0);
          acc[rg][it] = __builtin_amdgcn_mfma_f32_16x16x32_bf16(ahi[rg], blo, acc[rg][it], 0, 0, 0);
          acc[rg][it] = __builtin_amdgcn_mfma_f32_16x16x32_bf16(ahi[rg], bhi, acc[rg][it], 0, 0, 0);
        }
      }
    }
    #pragma unroll
    for (int it = 0; it < 2; it++){
      int t = w + it*4;
      if (t < 5){
        int col = t*16 + m16;
        float bb = bo[col];
        #pragma unroll
        for (int rg = 0; rg < 2; rg++){
          #pragma unroll
          for (int r2 = 0; r2 < 4; r2++){
            int rloc = rg*16 + q*4 + r2;
            int grow = row0 + rloc;
            float resid = (grow < N_NODES) ? h[(long)grow*80 + col] : 0.f;
            hs[rloc*84 + col] = acc[rg][it][r2] + bb + resid;
          }
        }
      }
    }
  }
  __syncthreads();

  // ---- stage 2: ffn1 — tiles w, w+4, w+8 of 12 (cols >= 160 phantoms)
  {
    f32x4 acc[2][3];
    #pragma unroll
    for (int rg = 0; rg < 2; rg++)
      #pragma unroll
      for (int it = 0; it < 3; it++) acc[rg][it] = (f32x4){0.f,0.f,0.f,0.f};
    #pragma unroll
    for (int kb = 0; kb < 3; kb++){
      int k0 = kb*32 + q*8;
      short8 ahi[2], alo[2];
      #pragma unroll
      for (int rg = 0; rg < 2; rg++){
        ahi[rg] = (short8)0; alo[rg] = (short8)0;
        if (k0 < 80){
          int rloc = rg*16 + m16;
          split8(&hs[rloc*84 + k0], ahi[rg], alo[rg]);
        }
      }
      #pragma unroll
      for (int it = 0; it < 3; it++){
        int t = w + it*4;
        long wi = ((long)(kb*192 + t*16 + m16))*32 + q*8;
        short8 bhi = *(const short8*)(Whi1 + wi);
        short8 blo = *(const short8*)(Wlo1 + wi);
        #pragma unroll
        for (int rg = 0; rg < 2; rg++){
          acc[rg][it] = __builtin_amdgcn_mfma_f32_16x16x32_bf16(alo[rg], bhi, acc[rg][it], 0, 0, 0);
          acc[rg][it] = __builtin_amdgcn_mfma_f32_16x16x32_bf16(ahi[rg], blo, acc[rg][it], 0, 0, 0);
          acc[rg][it] = __builtin_amdgcn_mfma_f32_16x16x32_bf16(ahi[rg], bhi, acc[rg][it], 0, 0, 0);
        }
      }
    }
    #pragma unroll
    for (int it = 0; it < 3; it++){
      int t = w + it*4;
      if (t < 10){
        int col = t*16 + m16;
        float bb = b1[col];
        #pragma unroll
        for (int rg = 0; rg < 2; rg++){
          #pragma unroll
          for (int r2 = 0; r2 < 4; r2++){
            int rloc = rg*16 + q*4 + r2;
            float val = fmaxf(acc[rg][it][r2] + bb, 0.f);
            short hi16, lo16; splitval(val, hi16, lo16);
            t_hi[rloc*168 + col] = hi16;
            t_lo[rloc*168 + col] = lo16;
          }
        }
      }
    }
  }
  __syncthreads();

  // ---- stage 3: ffn2 — K=160 from LDS, tiles w and w+4 of 8 (cols >= 80 phantoms)
  {
    f32x4 acc[2][2];
    #pragma unroll
    for (int rg = 0; rg < 2; rg++)
      #pragma unroll
      for (int it = 0; it < 2; it++) acc[rg][it] = (f32x4){0.f,0.f,0.f,0.f};
    #pragma unroll
    for (int kb = 0; kb < 5; kb++){
      int k0 = kb*32 + q*8;
      short8 ahi[2], alo[2];
      #pragma unroll
      for (int rg = 0; rg < 2; rg++){
        int rloc = rg*16 + m16;
        ahi[rg] = *(const short8*)(&t_hi[rloc*168 + k0]);
        alo[rg] = *(const short8*)(&t_lo[rloc*168 + k0]);
      }
      #pragma unroll
      for (int it = 0; it < 2; it++){
        int t = w + it*4;
        long wi = ((long)(kb*128 + t*16 + m16))*32 + q*8;
        short8 bhi = *(const short8*)(Whi2 + wi);
        short8 blo = *(const short8*)(Wlo2 + wi);
        #pragma unroll
        for (int rg = 0; rg < 2; rg++){
          acc[rg][it] = __builtin_amdgcn_mfma_f32_16x16x32_bf16(alo[rg], bhi, acc[rg][it], 0, 0, 0);
          acc[rg][it] = __builtin_amdgcn_mfma_f32_16x16x32_bf16(ahi[rg], blo, acc[rg][it], 0, 0, 0);
          acc[rg][it] = __builtin_amdgcn_mfma_f32_16x16x32_bf16(ahi[rg], bhi, acc[rg][it], 0, 0, 0);
        }
      }
    }
    #pragma unroll
    for (int it = 0; it < 2; it++){
      int t = w + it*4;
      if (t < 5){
        int col = t*16 + m16;
        float bb = b2[col];
        #pragma unroll
        for (int rg = 0; rg < 2; rg++){
          #pragma unroll
          for (int r2 = 0; r2 < 4; r2++){
            int rloc = rg*16 + q*4 + r2;
            int grow = row0 + rloc;
            if (grow < N_NODES)
              h[(long)grow*80 + col] = acc[rg][it][r2] + bb + hs[rloc*84 + col];
          }
        }
      }
    }
  }
}

// ---------------- edge-softmax attention: wave per node, interleaved KV ----------
// KV row per node: [K40|V40] fp32 (320 B contiguous, fully consumed per edge).
__global__ __launch_bounds__(256) void k_attn(
    float* __restrict__ Qg, const float* __restrict__ KV,
    const int* __restrict__ rowptr, const unsigned short* __restrict__ c16,
    const unsigned char* __restrict__ c8){
  int n = (blockIdx.x*256 + threadIdx.x) >> 6;
  int lane = threadIdx.x & 63;
  int el = lane >> 2;
  int hh = lane & 3;
  const float* qp = Qg + (long)n*40 + hh*10;
  float qv[10];
  #pragma unroll
  for (int i = 0; i < 5; i++){ float2 t = *(const float2*)(qp + 2*i); qv[2*i]=t.x; qv[2*i+1]=t.y; }
  float acc[10];
  #pragma unroll
  for (int i = 0; i < 10; i++) acc[i] = 0.f;
  float z = 0.f;
  int e0 = rowptr[n], e1 = rowptr[n+1];
  for (int j0 = e0; j0 < e1; j0 += 16){
    int j = j0 + el;
    bool valid = (j < e1);
    int jj = valid ? j : e0;
    int src = (int)c16[jj] | ((int)c8[jj] << 16);
    const float* kp = KV + (long)src*80 + hh*10;
    const float* vp = kp + 40;
    float dot = 0.f;
    #pragma unroll
    for (int i = 0; i < 5; i++){
      float2 kv = *(const float2*)(kp + 2*i);
      dot = fmaf(kv.x, qv[2*i], dot);
      dot = fmaf(kv.y, qv[2*i+1], dot);
    }
    float sc = fminf(fmaxf(dot * 0.31622776601683794f, -5.f), 5.f);
    float s = valid ? __expf(sc) : 0.f;
    z += s;
    #pragma unroll
    for (int i = 0; i < 5; i++){
      float2 vv = *(const float2*)(vp + 2*i);
      acc[2*i]   = fmaf(s, vv.x, acc[2*i]);
      acc[2*i+1] = fmaf(s, vv.y, acc[2*i+1]);
    }
  }
  #pragma unroll
  for (int m = 4; m <= 32; m <<= 1){
    z += __shfl_xor(z, m, 64);
    #pragma unroll
    for (int i = 0; i < 10; i++) acc[i] += __shfl_xor(acc[i], m, 64);
  }
  if (el == 0){
    float inv = 1.f / (z + 1e-6f);
    float* op = Qg + (long)n*40 + hh*10;
    #pragma unroll
    for (int i = 0; i < 5; i++){
      float2 o; o.x = acc[2*i]*inv; o.y = acc[2*i+1]*inv;
      *(float2*)(op + 2*i) = o;
    }
  }
}

// ---------------- MLP readout 80->40->20->4, fp32 output ----------------
__global__ __launch_bounds__(256) void k_readout(const float* __restrict__ h,
    const float* __restrict__ roF,
    float* __restrict__ out){
  __shared__ float w0[3200], w1[800], w2[80], bb0[40], bb1[20], bb2[4];
  int tid = threadIdx.x;
  for (int i = tid; i < 3200; i += 256) w0[i] = roF[i];
  for (int i = tid; i < 800;  i += 256) w1[i] = roF[3240 + i];
  if (tid < 80) w2[tid]  = roF[4060 + tid];
  if (tid < 40) bb0[tid] = roF[3200 + tid];
  if (tid < 20) bb1[tid] = roF[4040 + tid];
  if (tid < 4)  bb2[tid] = roF[4140 + tid];
  __syncthreads();
  int n = blockIdx.x*256 + tid;
  if (n >= N_NODES) return;
  float t0[40];
  #pragma unroll
  for (int c = 0; c < 40; c++) t0[c] = bb0[c];
  for (int k4 = 0; k4 < 20; k4++){
    float4 hv = *(const float4*)(h + (size_t)n*80 + k4*4);
    float hx[4] = {hv.x, hv.y, hv.z, hv.w};
    #pragma unroll
    for (int j = 0; j < 4; j++){
      int k = k4*4 + j;
      #pragma unroll
      for (int c = 0; c < 40; c++) t0[c] = fmaf(hx[j], w0[k*40 + c], t0[c]);
    }
  }
  float t1[20];
  #pragma unroll
  for (int c = 0; c < 20; c++) t1[c] = bb1[c];
  for (int k = 0; k < 40; k++){
    float a = fmaxf(t0[k], 0.f);
    #pragma unroll
    for (int c = 0; c < 20; c++) t1[c] = fmaf(a, w1[k*20 + c], t1[c]);
  }
  float o[4];
  #pragma unroll
  for (int c = 0; c < 4; c++) o[c] = bb2[c];
  for (int k = 0; k < 20; k++){
    float a = fmaxf(t1[k], 0.f);
    #pragma unroll
    for (int c = 0; c < 4; c++) o[c] = fmaf(a, w2[k*4 + c], o[c]);
  }
  #pragma unroll
  for (int c = 0; c < 4; c++) out[n*4 + c] = o[c];
}

// ---------------- launch ----------------
extern "C" void kernel_launch(void* const* d_in, const int* in_sizes, int n_in,
                              void* d_out, int out_size, void* d_ws, size_t ws_size,
                              hipStream_t stream){
  const void* x   = d_in[0];
  const int*  ei  = (const int*)d_in[1];
  const void* We  = d_in[2];
  const void* be  = d_in[3];
  const void* Wq  = d_in[4];
  const void* Wk  = d_in[5];
  const void* Wv  = d_in[6];
  const void* Wo  = d_in[7];
  const void* bo  = d_in[8];
  const void* W1  = d_in[9];
  const void* b1  = d_in[10];
  const void* W2  = d_in[11];
  const void* b2  = d_in[12];
  const void* Wr0 = d_in[13];
  const void* br0 = d_in[14];
  const void* Wr1 = d_in[15];
  const void* br1 = d_in[16];
  const void* Wr2 = d_in[17];
  const void* br2 = d_in[18];

  char* ws = (char*)d_ws;
  int*   flag   = (int*)(ws + 0);
  int*   eflag  = (int*)(ws + 4);
  int*   bsum   = (int*)(ws + 64);                 // 98 ints
  float* h      = (float*)(ws + 1024);             // 32,000,000
  float* B      = (float*)(ws + 32001024);         // 64,000,000
  short* Whi    = (short*)(ws + 96001024);         // 1,576,960
  short* Wlo    = (short*)(ws + 97577984);         // 1,576,960
  float* pfS    = (float*)(ws + 99154944);         // 32,576
  int*   rowptr = (int*)(ws + 99187520);           // 400,004
  unsigned short* c16 = (unsigned short*)(ws + 99587524);  // 2,000,000
  unsigned char*  c8  = (unsigned char*)(ws + 101587524);  // 1,000,000 -> end 102,587,524
  int*   cursor = (int*)B;                         // aliases B (dead before layers)
  float* out    = (float*)d_out;

  // B region slots (floats): R1 Q0/attn0 [N,40] @0 ; R2 KV shared [N,80] @4e6 ;
  // R3 Q1/attn1 [N,40] @12e6.  (g1's KV overwrites g0's after attn(g0) — stream order)
  float* R1 = B;
  float* R2 = B + 4000000;
  float* R3 = B + 12000000;

  const float* boF = pfS + 0;
  const float* b1F = pfS + 800;
  const float* b2F = pfS + 2400;
  const float* WeF = pfS + 3200;
  const float* beF = pfS + 3920;
  const float* roF = pfS + 4000;

  k_detect<<<1, 256, 0, stream>>>((const unsigned*)x, ei, flag, eflag);
  hipMemsetAsync(cursor, 0, N_NODES*sizeof(int), stream);
  k_count<<<(N_EDGES+255)/256, 256, 0, stream>>>(ei, cursor, eflag);
  k_scan1<<<98, 1024, 0, stream>>>(cursor, rowptr, bsum);
  k_scan2<<<1, 128, 0, stream>>>(bsum, rowptr);
  k_scan3<<<98, 1024, 0, stream>>>(rowptr, cursor, bsum);
  k_fill<<<(N_EDGES+255)/256, 256, 0, stream>>>(ei, cursor, c16, c8, eflag);
  k_prep<<<3112, 256, 0, stream>>>(Wq, Wk, Wv, Wo, W1, W2, bo, b1, b2, We, be,
                                   Wr0, br0, Wr1, br1, Wr2, br2, Whi, Wlo, pfS, flag);
  k_embed<<<(N_NODES*80)/256, 256, 0, stream>>>(x, WeF, beF, h, flag);

  const int qblk = (N_NODES + 127) / 128;   // 782
  const int pblk = (N_NODES + 31) / 32;     // 3125
  const int ablk = N_NODES / 4;             // 25000
  for (int l = 0; l < NLAYERS; l++){
    // group 0
    k_qkv<<<qblk, 256, 0, stream>>>(
        h, Whi + (l*2+0)*13824, Wlo + (l*2+0)*13824, R1, R2);
    k_attn<<<ablk, 256, 0, stream>>>(R1, R2, rowptr, c16, c8);
    // group 1 (KV overwrites R2 — g0's KV is dead)
    k_qkv<<<qblk, 256, 0, stream>>>(
        h, Whi + (l*2+1)*13824, Wlo + (l*2+1)*13824, R3, R2);
    k_attn<<<ablk, 256, 0, stream>>>(R3, R2, rowptr, c16, c8);
    // fused oproj + FFN
    k_post<<<pblk, 256, 0, stream>>>(
        R1, R3, h,
        Whi + 276480 + l*12288, Wlo + 276480 + l*12288,
        Whi + 399360 + l*18432, Wlo + 399360 + l*18432,
        Whi + 583680 + l*20480, Wlo + 583680 + l*20480,
        boF + l*80, b1F + l*160, b2F + l*80);
  }
  k_readout<<<(N_NODES+255)/256, 256, 0, stream>>>(h, roF, out);
}